// Round 9
// baseline (59.787 us; speedup 1.0000x reference)
//
#include <hip/hip_runtime.h>
#include <cstdint>

#define B8   8
#define DIN  1024
#define NH1  2048
#define NH2  1024
#define NOUT 5120
#define TKS  5      // tropical k-split (5120 = 5 * 1024)

__device__ __forceinline__ float4 ld4(const float* p) {
  return *reinterpret_cast<const float4*>(p);
}
__device__ __forceinline__ void st4(float* p, float4 v) {
  *reinterpret_cast<float4*>(p) = v;
}

// C_parts[kb][8][N] = A[8, k0:k0+KC] @ W[k0:k0+KC, :]   (partial over K-chunk)
// A source: raw input (NPART==0) or sum of NPART partials + bias (+ReLU).
// The staged (finalized) A chunk is optionally written out (features).
template<int K, int N, int KSPLIT, int NPART, bool RELU_IN, bool WRITE_STAGE>
__global__ __launch_bounds__(256)
void gemm8(const float* __restrict__ Asrc, const float* __restrict__ bias_in,
           const float* __restrict__ W, float* __restrict__ Cparts,
           float* __restrict__ stage_out)
{
  constexpr int KC    = K / KSPLIT;   // k-chunk per block
  constexpr int KC4   = KC / 4;
  constexpr int NCOLB = N / 64;       // 64 output cols per block
  constexpr int KT    = KC / 16;      // k elements per thread

  __shared__ float A_lds[8][KC];      // <= 8 KB
  __shared__ float red[16][8][64];    // 32 KB

  const int tid = threadIdx.x;
  const int kb  = blockIdx.x / NCOLB;
  const int cb  = blockIdx.x % NCOLB;
  const int k0  = kb * KC;

  // ---- stage A chunk into LDS (finalize previous stage: sum partials + bias + relu)
  for (int e = tid; e < 8 * KC4; e += 256) {
    const int b = e / KC4, k4 = e - b * KC4;
    float4 v;
    if constexpr (NPART == 0) {
      v = ld4(&Asrc[(size_t)b * K + k0 + 4 * k4]);
    } else {
      v = ld4(&bias_in[k0 + 4 * k4]);
      #pragma unroll
      for (int p = 0; p < NPART; ++p) {
        float4 t = ld4(&Asrc[((size_t)p * 8 + b) * K + k0 + 4 * k4]);
        v.x += t.x; v.y += t.y; v.z += t.z; v.w += t.w;
      }
      if constexpr (RELU_IN) {
        v.x = fmaxf(v.x, 0.f); v.y = fmaxf(v.y, 0.f);
        v.z = fmaxf(v.z, 0.f); v.w = fmaxf(v.w, 0.f);
      }
    }
    st4(&A_lds[b][4 * k4], v);
    if constexpr (WRITE_STAGE) {
      if (cb == 0) st4(&stage_out[(size_t)b * K + k0 + 4 * k4], v);
    }
  }
  __syncthreads();

  // ---- main loop: 16 col-groups (float4) x 16 k-slices
  const int g  = tid & 15, ks = tid >> 4;
  const int c0 = cb * 64 + g * 4;
  float4 acc[8];
  #pragma unroll
  for (int b = 0; b < 8; ++b) acc[b] = make_float4(0.f, 0.f, 0.f, 0.f);

  const float* Wp = &W[(size_t)(k0 + ks * KT) * N + c0];
  #pragma unroll
  for (int i = 0; i < KT; i += 4) {
    const float4 w0 = ld4(Wp + (size_t)(i + 0) * N);
    const float4 w1 = ld4(Wp + (size_t)(i + 1) * N);
    const float4 w2 = ld4(Wp + (size_t)(i + 2) * N);
    const float4 w3 = ld4(Wp + (size_t)(i + 3) * N);
    const int kk = ks * KT + i;
    #pragma unroll
    for (int b = 0; b < 8; ++b) {
      const float4 a = ld4(&A_lds[b][kk]);   // broadcast within 16-lane group
      acc[b].x += a.x * w0.x + a.y * w1.x + a.z * w2.x + a.w * w3.x;
      acc[b].y += a.x * w0.y + a.y * w1.y + a.z * w2.y + a.w * w3.y;
      acc[b].z += a.x * w0.z + a.y * w1.z + a.z * w2.z + a.w * w3.z;
      acc[b].w += a.x * w0.w + a.y * w1.w + a.z * w2.w + a.w * w3.w;
    }
  }

  // ---- reduce the 16 k-slices through LDS
  __syncthreads();
  #pragma unroll
  for (int b = 0; b < 8; ++b) st4(&red[ks][b][g * 4], acc[b]);
  __syncthreads();

  for (int p = tid; p < 512; p += 256) {
    const int c = p & 63, b = p >> 6;
    float s = 0.f;
    #pragma unroll
    for (int j = 0; j < 16; ++j) s += red[j][b][c];
    Cparts[((size_t)kb * 8 + b) * N + cb * 64 + c] = s;
  }
}

// logits[8][5120] = sum of 4 partials + b3
__global__ __launch_bounds__(256)
void finalize_logits(const float* __restrict__ parts, const float* __restrict__ b3,
                     float* __restrict__ logits)
{
  const int i  = blockIdx.x * 256 + threadIdx.x;   // 10240 float4s, grid exact
  const int b  = i / 1280, k4 = i - b * 1280;
  float4 v = ld4(&b3[4 * k4]);
  #pragma unroll
  for (int p = 0; p < 4; ++p) {
    const float4 t = ld4(&parts[((size_t)p * 8 + b) * NOUT + 4 * k4]);
    v.x += t.x; v.y += t.y; v.z += t.z; v.w += t.w;
  }
  st4(&logits[(size_t)b * NOUT + 4 * k4], v);
}

// tpart[ks][b][o] = max_{k in chunk ks} logits[b][k] * CM[o][k]
// WAVE-CONCURRENCY version: R7's rolled no-buffering shape, but 6400 waves
// (grid 320 x 5 kchunks x 4 waves) instead of 2560 -> 25/CU available
// (16+/CU resident at the VGPR cap). 4 rows/wave keeps logits L2 traffic
// at 205 MB. No LDS, no barriers, no manual buffering (R3/R5 spill lesson).
__global__ __launch_bounds__(256, 4)
void tropical4w(const float* __restrict__ logits, const float* __restrict__ CM,
                float* __restrict__ tpart)
{
  const int tid = threadIdx.x;
  const int w   = tid >> 6;      // wave 0..3
  const int l   = tid & 63;      // lane
  const int ks  = blockIdx.y;    // k-chunk 0..4
  const int k0  = ks * 1024;
  const int o0  = (blockIdx.x * 4 + w) * 4;   // this wave's 4 rows

  const float* cmb = &CM[(size_t)o0 * NOUT + k0 + 4 * l];
  const float* lg  = &logits[k0 + 4 * l];

  float pm0[8], pm1[8], pm2[8], pm3[8];
  #pragma unroll
  for (int b = 0; b < 8; ++b) {
    pm0[b] = -3.402823466e38f; pm1[b] = -3.402823466e38f;
    pm2[b] = -3.402823466e38f; pm3[b] = -3.402823466e38f;
  }

  for (int j = 0; j < 4; ++j) {          // rolled: let the compiler schedule
    const int off = 256 * j;             // 64 lanes * float4
    const float4 c0 = ld4(cmb + off);
    const float4 c1 = ld4(cmb + (size_t)1 * NOUT + off);
    const float4 c2 = ld4(cmb + (size_t)2 * NOUT + off);
    const float4 c3 = ld4(cmb + (size_t)3 * NOUT + off);
    #pragma unroll
    for (int b = 0; b < 8; ++b) {
      const float4 lv = ld4(lg + (size_t)b * NOUT + off);
      float t0, t1;
      t0 = fmaxf(lv.x * c0.x, lv.y * c0.y);
      t1 = fmaxf(lv.z * c0.z, lv.w * c0.w);
      pm0[b] = fmaxf(pm0[b], fmaxf(t0, t1));
      t0 = fmaxf(lv.x * c1.x, lv.y * c1.y);
      t1 = fmaxf(lv.z * c1.z, lv.w * c1.w);
      pm1[b] = fmaxf(pm1[b], fmaxf(t0, t1));
      t0 = fmaxf(lv.x * c2.x, lv.y * c2.y);
      t1 = fmaxf(lv.z * c2.z, lv.w * c2.w);
      pm2[b] = fmaxf(pm2[b], fmaxf(t0, t1));
      t0 = fmaxf(lv.x * c3.x, lv.y * c3.y);
      t1 = fmaxf(lv.z * c3.z, lv.w * c3.w);
      pm3[b] = fmaxf(pm3[b], fmaxf(t0, t1));
    }
  }

  // cross-lane max reduce; lane 0 writes tpart[ks][b][o0+r]
  float* tp = &tpart[(size_t)ks * 8 * NOUT];
  #pragma unroll
  for (int b = 0; b < 8; ++b) {
    float v0 = pm0[b], v1 = pm1[b], v2 = pm2[b], v3 = pm3[b];
    for (int m = 32; m; m >>= 1) {
      v0 = fmaxf(v0, __shfl_xor(v0, m));
      v1 = fmaxf(v1, __shfl_xor(v1, m));
      v2 = fmaxf(v2, __shfl_xor(v2, m));
      v3 = fmaxf(v3, __shfl_xor(v3, m));
    }
    if (l == 0) {
      tp[(size_t)b * NOUT + o0 + 0] = v0;
      tp[(size_t)b * NOUT + o0 + 1] = v1;
      tp[(size_t)b * NOUT + o0 + 2] = v2;
      tp[(size_t)b * NOUT + o0 + 3] = v3;
    }
  }
}

// out[b][o] = max_ks tpart[ks][b][o]
__global__ __launch_bounds__(256)
void tropical_combine(const float* __restrict__ tpart, float* __restrict__ out)
{
  const int i = blockIdx.x * 256 + threadIdx.x;   // 10240 float4s, grid exact
  float4 v = ld4(&tpart[4 * (size_t)i]);
  #pragma unroll
  for (int p = 1; p < TKS; ++p) {
    const float4 t = ld4(&tpart[(size_t)p * 8 * NOUT + 4 * (size_t)i]);
    v.x = fmaxf(v.x, t.x); v.y = fmaxf(v.y, t.y);
    v.z = fmaxf(v.z, t.z); v.w = fmaxf(v.w, t.w);
  }
  st4(&out[4 * (size_t)i], v);
}

extern "C" void kernel_launch(void* const* d_in, const int* in_sizes, int n_in,
                              void* d_out, int out_size, void* d_ws, size_t ws_size,
                              hipStream_t stream)
{
  const float* x  = (const float*)d_in[0];
  const float* W1 = (const float*)d_in[1];
  const float* b1 = (const float*)d_in[2];
  const float* W2 = (const float*)d_in[3];
  const float* b2 = (const float*)d_in[4];
  const float* W3 = (const float*)d_in[5];
  const float* b3 = (const float*)d_in[6];
  const float* CM = (const float*)d_in[7];

  float* out  = (float*)d_out;            // [8][5120]
  float* feat = out + B8 * NOUT;          // [8][1024]

  float* ws      = (float*)d_ws;
  float* parts1  = ws;                      // [ 8][8][2048] = 131072 f
  float* parts2  = parts1 + 8  * 8 * NH1;   // [16][8][1024] = 131072 f
  float* parts3  = parts2 + 16 * 8 * NH2;   // [ 4][8][5120] = 163840 f
  float* logits  = parts3 + 4  * 8 * NOUT;  // [8][5120]     =  40960 f
  float* tpart   = logits + 8 * NOUT;       // [5][8][5120]  = 204800 f

  // h1 partials: x[8,1024] @ W1[1024,2048], K split 8 -> 256 blocks
  gemm8<DIN, NH1, 8, 0, false, false><<<256, 256, 0, stream>>>(x, nullptr, W1, parts1, nullptr);
  // h2 partials: relu(sum parts1 + b1) @ W2[2048,1024], K split 16 -> 256 blocks
  gemm8<NH1, NH2, 16, 8, true, false><<<256, 256, 0, stream>>>(parts1, b1, W2, parts2, nullptr);
  // logits partials: relu(sum parts2 + b2) @ W3[1024,5120], K split 4 -> 320 blocks
  // (staged A == features; written by cb==0 blocks)
  gemm8<NH2, NOUT, 4, 16, true, true><<<320, 256, 0, stream>>>(parts2, b2, W3, parts3, feat);
  // logits = sum parts3 + b3
  finalize_logits<<<40, 256, 0, stream>>>(parts3, b3, logits);
  // tropical: 320 rowblocks x 5 kchunks, 4 waves x 4 rows each -> 6400 waves
  {
    dim3 grid(320, TKS);
    tropical4w<<<grid, 256, 0, stream>>>(logits, CM, tpart);
  }
  // fold k-chunks
  tropical_combine<<<40, 256, 0, stream>>>(tpart, out);
}